// Round 6
// baseline (118.957 us; speedup 1.0000x reference)
//
#include <hip/hip_runtime.h>

#define NPTS 16384
#define TH 33.33f

typedef __attribute__((ext_vector_type(8)))  __bf16 bf16x8;
typedef __attribute__((ext_vector_type(16))) float  f32x16;

__device__ __forceinline__ unsigned short f2bf(float x) {
    unsigned u = __float_as_uint(x);
    u += 0x7FFFu + ((u >> 16) & 1u);
    return (unsigned short)(u >> 16);
}
__device__ __forceinline__ float bf2f(unsigned short h) {
    return __uint_as_float(((unsigned)h) << 16);
}

union U8 { unsigned short s[8]; uint4 v; };

// ws: mats ushort[2b][4roles][512 tiles][512] (4 MB), harr float[2b][2set][NPTS] (256 KB),
//     d2min uint[4db][NPTS] (256 KB; clamped dist float bits, nonneg -> uint-ordered)
// fragment: elem = tile*512 + (g*32 + (p&31))*8 + j, k = g*8+j
// A k: [qh(3), ql(3), qh(2) | zh, 1,1,1, 0..0]   B k: [ph(3), ph(3), pl(2) | zl, -hp0,-hp1,-hp2, 0..0]
// MFMA score s = qh.ph + ql.ph + qh.pl - hp ~= q.p - hp ;  d^2 = 2*(hq - s)

__global__ __launch_bounds__(256) void prep_kernel(const float* __restrict__ src,
        const float* __restrict__ tgt, unsigned short* __restrict__ mats,
        float* __restrict__ harr, unsigned int* __restrict__ d2min,
        float* __restrict__ out) {
    int t = blockIdx.x * 256 + threadIdx.x;       // 65536 threads
    if (t < 2) out[t] = 0.0f;
    d2min[t] = 0x7F800000u;                       // +inf init (4*NPTS entries)
    int b = t >> 15, set = (t >> 14) & 1, p = t & (NPTS - 1);
    const float* pc = (set ? tgt : src) + ((size_t)b * NPTS + p) * 3;
    float x = pc[0], y = pc[1], z = pc[2];
    float hp = 0.5f * fmaf(z, z, fmaf(y, y, x * x));
    harr[(b * 2 + set) * NPTS + p] = hp;
    unsigned short xh = f2bf(x), yh = f2bf(y), zh = f2bf(z);
    unsigned short xl = f2bf(x - bf2f(xh)), yl = f2bf(y - bf2f(yh)), zl = f2bf(z - bf2f(zh));
    float r = hp;
    unsigned short h0 = f2bf(r); r -= bf2f(h0);
    unsigned short h1 = f2bf(r); r -= bf2f(h1);
    unsigned short h2 = f2bf(r);
    unsigned short n0 = h0 ^ 0x8000, n1 = h1 ^ 0x8000, n2 = h2 ^ 0x8000;
    const unsigned short one = 0x3F80;
    U8 a0, a1, c0, c1;
    a0.s[0]=xh; a0.s[1]=yh; a0.s[2]=zh; a0.s[3]=xl; a0.s[4]=yl; a0.s[5]=zl; a0.s[6]=xh; a0.s[7]=yh;
    a1.s[0]=zh; a1.s[1]=one; a1.s[2]=one; a1.s[3]=one; a1.s[4]=0; a1.s[5]=0; a1.s[6]=0; a1.s[7]=0;
    c0.s[0]=xh; c0.s[1]=yh; c0.s[2]=zh; c0.s[3]=xh; c0.s[4]=yh; c0.s[5]=zh; c0.s[6]=xl; c0.s[7]=yl;
    c1.s[0]=zl; c1.s[1]=n0; c1.s[2]=n1; c1.s[3]=n2; c1.s[4]=0; c1.s[5]=0; c1.s[6]=0; c1.s[7]=0;
    size_t tile = p >> 5; int ll = p & 31;
    size_t iA = ((size_t)(b * 4 + set))     * NPTS * 16 + tile * 512 + ll * 8;
    size_t iB = ((size_t)(b * 4 + 2 + set)) * NPTS * 16 + tile * 512 + ll * 8;
    *(uint4*)(mats + iA)       = a0.v;
    *(uint4*)(mats + iA + 256) = a1.v;
    *(uint4*)(mats + iB)       = c0.v;
    *(uint4*)(mats + iB + 256) = c1.v;
}

#define FOLD2(MM, AA) { \
    f32x16 t0 = __builtin_amdgcn_mfma_f32_32x32x16_bf16(AA, p0, zc, 0, 0, 0); \
    f32x16 t1 = __builtin_amdgcn_mfma_f32_32x32x16_bf16(AA, p1, zc, 0, 0, 0); \
    _Pragma("unroll") for (int j = 0; j < 16; j++) MM[j] = fmaxf(fmaxf(t0[j], t1[j]), MM[j]); }

#define EPILOG(MM, P) { \
    float* sc = &scratch[wave][0][0]; \
    _Pragma("unroll") for (int j = 0; j < 16; j++) { \
        int r0 = (j & 3) + 8 * (j >> 2) + 4 * g; sc[r0 * 33 + cc] = MM[j]; } \
    __syncthreads(); \
    const float* sr = &scratch[wave][0][0] + cc * 33 + g * 16; \
    float mx = -3.0e38f; \
    _Pragma("unroll") for (int k = 0; k < 16; k++) mx = fmaxf(mx, sr[k]); \
    mx = fmaxf(mx, __shfl_xor(mx, 32, 64)); \
    if (lane < 32) { \
        int grow = (rt0 + (P)) * 32 + lane; \
        float hq = hqbase[grow]; \
        float d2 = 2.0f * (hq - mx); \
        float d = fminf(sqrtf(fmaxf(d2, 0.0f)), TH); \
        atomicMin(&dmin[grow], __float_as_uint(d)); } \
    __syncthreads(); }

__global__ __launch_bounds__(256, 3) void gemm_kernel(const unsigned short* __restrict__ mats,
        const float* __restrict__ harr, unsigned int* __restrict__ d2min) {
    const int db = blockIdx.y, dir = db >> 1, b = db & 1;
    const int rowblock = blockIdx.x >> 3, seg = blockIdx.x & 7;
    const int tid = threadIdx.x, wave = tid >> 6, lane = tid & 63;
    const int g = lane >> 5, cc = lane & 31;
    const unsigned short* Am = mats + ((size_t)(b * 4 + dir))     * NPTS * 16;
    const unsigned short* Bm = mats + ((size_t)(b * 4 + 3 - dir)) * NPTS * 16;

    const int rt0 = rowblock * 16 + wave * 4;     // 4 row-tiles = 128 rows per wave
    bf16x8 a0 = *(const bf16x8*)(Am + (size_t)(rt0 + 0) * 512 + lane * 8);
    bf16x8 a1 = *(const bf16x8*)(Am + (size_t)(rt0 + 1) * 512 + lane * 8);
    bf16x8 a2 = *(const bf16x8*)(Am + (size_t)(rt0 + 2) * 512 + lane * 8);
    bf16x8 a3 = *(const bf16x8*)(Am + (size_t)(rt0 + 3) * 512 + lane * 8);

    __shared__ float scratch[4][32][33];          // 16.9 KB epilogue scratch

    f32x16 m0 = -3.0e38f, m1 = -3.0e38f, m2 = -3.0e38f, m3 = -3.0e38f;
    const f32x16 zc = 0.0f;

    // barrier-free: each wave streams its segment's 64 col-tiles global->VGPR,
    // 2-tile software pipeline (L2-resident; ~7 us aggregate @ 35 TB/s)
    const unsigned short* bp = Bm + (size_t)seg * 64 * 512 + lane * 8;
    bf16x8 p0 = *(const bf16x8*)(bp);
    bf16x8 p1 = *(const bf16x8*)(bp + 512);
#pragma unroll 1
    for (int ct = 0; ct < 64; ct += 2) {
        int nct = (ct + 2 < 64) ? ct + 2 : 62;    // unconditional prefetch (tail re-reads)
        bf16x8 n0 = *(const bf16x8*)(bp + (size_t)nct * 512);
        bf16x8 n1 = *(const bf16x8*)(bp + (size_t)nct * 512 + 512);
        FOLD2(m0, a0)
        FOLD2(m1, a1)
        FOLD2(m2, a2)
        FOLD2(m3, a3)
        p0 = n0; p1 = n1;
    }

    const float* hqbase = harr + (size_t)(b * 2 + dir) * NPTS;
    unsigned int* dmin = d2min + (size_t)db * NPTS;
    EPILOG(m0, 0)
    EPILOG(m1, 1)
    EPILOG(m2, 2)
    EPILOG(m3, 3)
}

__global__ __launch_bounds__(256) void merge_kernel(const unsigned int* __restrict__ d2min,
                                                    float* __restrict__ out) {
    int i = blockIdx.x * 256 + threadIdx.x;       // 16384 threads
    float a0 = __uint_as_float(d2min[0 * NPTS + i]) + __uint_as_float(d2min[2 * NPTS + i]);
    float a1 = __uint_as_float(d2min[1 * NPTS + i]) + __uint_as_float(d2min[3 * NPTS + i]);
#pragma unroll
    for (int off = 32; off > 0; off >>= 1) {
        a0 += __shfl_down(a0, off, 64);
        a1 += __shfl_down(a1, off, 64);
    }
    __shared__ float w0[4], w1[4];
    int wv = threadIdx.x >> 6;
    if ((threadIdx.x & 63) == 0) { w0[wv] = a0; w1[wv] = a1; }
    __syncthreads();
    if (threadIdx.x == 0) {
        const float inv = 1.0f / (2.0f * NPTS);
        atomicAdd(&out[0], (w0[0] + w0[1] + w0[2] + w0[3]) * inv);
        atomicAdd(&out[1], (w1[0] + w1[1] + w1[2] + w1[3]) * inv);
    }
}

extern "C" void kernel_launch(void* const* d_in, const int* in_sizes, int n_in,
                              void* d_out, int out_size, void* d_ws, size_t ws_size,
                              hipStream_t stream) {
    const float* src = (const float*)d_in[0];
    const float* tgt = (const float*)d_in[1];
    float* out = (float*)d_out;
    unsigned short* mats = (unsigned short*)d_ws;                          // 4 MB
    float* harr = (float*)((char*)d_ws + 4194304);                         // 256 KB
    unsigned int* d2min = (unsigned int*)((char*)d_ws + 4194304 + 262144); // 256 KB

    prep_kernel<<<256, 256, 0, stream>>>(src, tgt, mats, harr, d2min, out);
    gemm_kernel<<<dim3(256, 4), 256, 0, stream>>>(mats, harr, d2min);
    merge_kernel<<<64, 256, 0, stream>>>(d2min, out);
}

// Round 8
// 108.569 us; speedup vs baseline: 1.0957x; 1.0957x over previous
//
#include <hip/hip_runtime.h>

#define NPTS 16384
#define TH 33.33f

typedef __attribute__((ext_vector_type(8)))  __bf16 bf16x8;
typedef __attribute__((ext_vector_type(16))) float  f32x16;

__device__ __forceinline__ unsigned short f2bf(float x) {
    unsigned u = __float_as_uint(x);
    u += 0x7FFFu + ((u >> 16) & 1u);
    return (unsigned short)(u >> 16);
}
__device__ __forceinline__ float bf2f(unsigned short h) {
    return __uint_as_float(((unsigned)h) << 16);
}

union UV { uint4 v; bf16x8 h; unsigned short s[8]; };

// ws: d2part float[4 db][32 rowblock][8 seg][512]  (2 MB) — every slot written exactly
// once by its (block,seg) owner -> no init pass, no atomics, no races.
// fragment map: elem = (g*32 + idx)*8 + j with k = g*8 + j (A/B symmetric, verified R2-R7)
// A k: [qh(3), ql(3), qh(2) | zh, 1,1,1, 0..0]   B k: [ph(3), ph(3), pl(2) | zl, -hp0,-hp1,-hp2, 0..0]
// MFMA score s = qh.ph + ql.ph + qh.pl - hp ~= q.p - hp ;  d^2 = 2*(hq - s)

// NOTE: MFMA results must be consumed by compiler-known VALU ops only (fmaxf).
// Inline-asm consumers skip the MFMA-write->VALU-read hazard recognizer (R5/R7 failures).
#define FOLD2(MM, AA) { \
    f32x16 t0 = __builtin_amdgcn_mfma_f32_32x32x16_bf16(AA, q0, zc, 0, 0, 0); \
    f32x16 t1 = __builtin_amdgcn_mfma_f32_32x32x16_bf16(AA, q1, zc, 0, 0, 0); \
    _Pragma("unroll") for (int j = 0; j < 16; j++) MM[j] = fmaxf(fmaxf(t0[j], t1[j]), MM[j]); }

// stage chunk CC (512 B-points) as MFMA fragments into LDS buffer BUF (16 KB)
#define PREP_CHUNK(CC, BUF) { \
    unsigned short* lb = (unsigned short*)(smem + (BUF) * 16384); \
    _Pragma("unroll") for (int u = 0; u < 2; u++) { \
        int k = tid * 2 + u; \
        int gp = seg * 2048 + (CC) * 512 + k; \
        float x = pp[gp * 3 + 0], y = pp[gp * 3 + 1], z = pp[gp * 3 + 2]; \
        float hp = 0.5f * fmaf(z, z, fmaf(y, y, x * x)); \
        unsigned short xh = f2bf(x), yh = f2bf(y), zh = f2bf(z); \
        unsigned short xl = f2bf(x - bf2f(xh)), yl = f2bf(y - bf2f(yh)), zl = f2bf(z - bf2f(zh)); \
        float rr = hp; \
        unsigned short h0 = f2bf(rr); rr -= bf2f(h0); \
        unsigned short h1 = f2bf(rr); rr -= bf2f(h1); \
        unsigned short h2 = f2bf(rr); \
        UV c0, c1; \
        c0.s[0]=xh; c0.s[1]=yh; c0.s[2]=zh; c0.s[3]=xh; c0.s[4]=yh; c0.s[5]=zh; c0.s[6]=xl; c0.s[7]=yl; \
        c1.s[0]=zl; c1.s[1]=(unsigned short)(h0^0x8000); c1.s[2]=(unsigned short)(h1^0x8000); \
        c1.s[3]=(unsigned short)(h2^0x8000); c1.s[4]=0; c1.s[5]=0; c1.s[6]=0; c1.s[7]=0; \
        int t = k >> 5, pos = k & 31; \
        *(uint4*)(lb + t * 512 + pos * 8)       = c0.v; \
        *(uint4*)(lb + t * 512 + 256 + pos * 8) = c1.v; } }

#define EPILOG(MM, P) { \
    float* sc = scratch + wave * 1056; \
    _Pragma("unroll") for (int j = 0; j < 16; j++) { \
        int r0 = (j & 3) + 8 * (j >> 2) + 4 * g; sc[r0 * 33 + cc] = MM[j]; } \
    __syncthreads(); \
    const float* sr = sc + cc * 33 + g * 16; \
    float mx = -3.0e38f; \
    _Pragma("unroll") for (int k = 0; k < 16; k++) mx = fmaxf(mx, sr[k]); \
    mx = fmaxf(mx, __shfl_xor(mx, 32, 64)); \
    if (lane < 32) { \
        float d2 = 2.0f * (hq[P] - mx); \
        float d = fminf(sqrtf(fmaxf(d2, 0.0f)), TH); \
        dst[wave * 128 + (P) * 32 + lane] = d; } \
    __syncthreads(); }

__global__ __launch_bounds__(256, 3) void chamfer_kernel(
        const float* __restrict__ src, const float* __restrict__ tgt,
        float* __restrict__ d2part)
{
    const int db = blockIdx.y, dir = db >> 1, b = db & 1;
    const int rowblock = blockIdx.x >> 3, seg = blockIdx.x & 7;
    const int tid = threadIdx.x, wave = tid >> 6, lane = tid & 63;
    const int g = lane >> 5, cc = lane & 31;
    const float* qp = (dir == 0 ? src : tgt) + (size_t)b * NPTS * 3;
    const float* pp = (dir == 0 ? tgt : src) + (size_t)b * NPTS * 3;
    const unsigned short one = 0x3F80;

    // 32 KB: two 16 KB B-stage buffers; aliased as epilogue scratch after the loop
    __shared__ alignas(16) unsigned char smem[32768];
    float* scratch = (float*)smem;   // 4 waves * 32 rows * 33 floats = 16.9 KB

    // ---- A fragments + hq: registers only, each lane preps its own rows ----
    const int rt0 = rowblock * 16 + wave * 4;     // 4 row-tiles = 128 rows per wave
    bf16x8 afrag[4]; float hq[4];
#pragma unroll
    for (int i = 0; i < 4; i++) {
        int r = (rt0 + i) * 32 + cc;
        float x = qp[r * 3 + 0], y = qp[r * 3 + 1], z = qp[r * 3 + 2];
        hq[i] = 0.5f * fmaf(z, z, fmaf(y, y, x * x));
        unsigned short xh = f2bf(x), yh = f2bf(y), zh = f2bf(z);
        unsigned short xl = f2bf(x - bf2f(xh)), yl = f2bf(y - bf2f(yh)), zl = f2bf(z - bf2f(zh));
        UV f0, f1, rv;
        f0.s[0]=xh; f0.s[1]=yh; f0.s[2]=zh; f0.s[3]=xl; f0.s[4]=yl; f0.s[5]=zl; f0.s[6]=xh; f0.s[7]=yh;
        f1.s[0]=zh; f1.s[1]=one; f1.s[2]=one; f1.s[3]=one; f1.s[4]=0; f1.s[5]=0; f1.s[6]=0; f1.s[7]=0;
        rv.v = g ? f1.v : f0.v;
        afrag[i] = rv.h;
    }

    f32x16 m0 = -3.0e38f, m1 = -3.0e38f, m2 = -3.0e38f, m3 = -3.0e38f;
    const f32x16 zc = 0.0f;

    PREP_CHUNK(0, 0)
    __syncthreads();
#pragma unroll 1
    for (int c = 0; c < 4; ++c) {                 // 4 chunks x 16 col-tiles
        if (c < 3) { PREP_CHUNK(c + 1, (c + 1) & 1) }   // stage next while computing
        const unsigned short* bb = (const unsigned short*)(smem + (c & 1) * 16384);
#pragma unroll 1
        for (int pt = 0; pt < 8; ++pt) {          // 2 col-tiles per iter
            bf16x8 q0 = *(const bf16x8*)(bb + pt * 1024 + lane * 8);
            bf16x8 q1 = *(const bf16x8*)(bb + pt * 1024 + 512 + lane * 8);
            FOLD2(m0, afrag[0])
            FOLD2(m1, afrag[1])
            FOLD2(m2, afrag[2])
            FOLD2(m3, afrag[3])
        }
        __syncthreads();
    }

    float* dst = d2part + (((size_t)(db * 32 + rowblock)) * 8 + seg) * 512;
    EPILOG(m0, 0)
    EPILOG(m1, 1)
    EPILOG(m2, 2)
    EPILOG(m3, 3)
}

__global__ __launch_bounds__(1024) void merge_kernel(const float* __restrict__ d2part,
                                                     float* __restrict__ out) {
    const int b = blockIdx.x;                     // 0..1 (batch)
    const int tid = threadIdx.x;
    float s = 0.0f;
#pragma unroll
    for (int pass = 0; pass < 2; pass++) {        // dir 0 (db=b) and dir 1 (db=2+b)
        const float* base = d2part + (size_t)(pass * 2 + b) * 32 * 8 * 512;
        for (int r = tid; r < NPTS; r += 1024) {
            const float* p = base + (size_t)(r >> 9) * 4096 + (r & 511);
            float m = p[0];
#pragma unroll
            for (int sgi = 1; sgi < 8; sgi++) m = fminf(m, p[sgi * 512]);
            s += m;
        }
    }
#pragma unroll
    for (int off = 32; off > 0; off >>= 1) s += __shfl_down(s, off, 64);
    __shared__ float w[16];
    if ((tid & 63) == 0) w[tid >> 6] = s;
    __syncthreads();
    if (tid == 0) {
        float t = 0.0f;
#pragma unroll
        for (int i = 0; i < 16; i++) t += w[i];
        out[b] = t * (1.0f / (2.0f * NPTS));      // (mean_fwd + mean_bwd) / 2
    }
}

extern "C" void kernel_launch(void* const* d_in, const int* in_sizes, int n_in,
                              void* d_out, int out_size, void* d_ws, size_t ws_size,
                              hipStream_t stream) {
    const float* src = (const float*)d_in[0];
    const float* tgt = (const float*)d_in[1];
    float* out = (float*)d_out;
    float* d2part = (float*)d_ws;                 // 2 MB, write-once (no init needed)

    chamfer_kernel<<<dim3(256, 4), 256, 0, stream>>>(src, tgt, d2part);
    merge_kernel<<<2, 1024, 0, stream>>>(d2part, out);
}

// Round 9
// 99.210 us; speedup vs baseline: 1.1990x; 1.0943x over previous
//
#include <hip/hip_runtime.h>

#define NPTS 16384
#define TH 33.33f

typedef __attribute__((ext_vector_type(8)))  __bf16 bf16x8;
typedef __attribute__((ext_vector_type(16))) float  f32x16;

__device__ __forceinline__ unsigned short f2bf(float x) {
    unsigned u = __float_as_uint(x);
    u += 0x7FFFu + ((u >> 16) & 1u);
    return (unsigned short)(u >> 16);
}
__device__ __forceinline__ float bf2f(unsigned short h) {
    return __uint_as_float(((unsigned)h) << 16);
}

union UV { uint4 v; bf16x8 h; unsigned short s[8]; };

// ws: d2part float[4 db][32 rowblock][8 seg][512]  (2 MB) — every slot written exactly
// once by its (block,seg) owner -> no init pass, no atomics, no races.
// fragment map: elem = (g*32 + idx)*8 + j with k = g*8 + j (A/B symmetric, verified R2-R8)
// A k: [qh(3), ql(3), qh(2) | zh, 1,1,1, 0..0]   B k: [ph(3), ph(3), pl(2) | zl, -hp0,-hp1,-hp2, 0..0]
// MFMA score s = qh.ph + ql.ph + qh.pl - hp ~= q.p - hp ;  d^2 = 2*(hq - s)

// NOTE: MFMA results must be consumed by compiler-known VALU ops only (fmaxf).
// Inline-asm consumers skip the MFMA-write->VALU-read hazard recognizer (R5/R7 failures).
#define FOLD2(MM, AA) { \
    f32x16 t0 = __builtin_amdgcn_mfma_f32_32x32x16_bf16(AA, q0, zc, 0, 0, 0); \
    f32x16 t1 = __builtin_amdgcn_mfma_f32_32x32x16_bf16(AA, q1, zc, 0, 0, 0); \
    _Pragma("unroll") for (int j = 0; j < 16; j++) MM[j] = fmaxf(fmaxf(t0[j], t1[j]), MM[j]); }

// stage chunk CC (512 B-points) as MFMA fragments into LDS buffer BUF (16 KB)
#define PREP_CHUNK(CC, BUF) { \
    unsigned short* lb = (unsigned short*)(smem + (BUF) * 16384); \
    _Pragma("unroll") for (int u = 0; u < 2; u++) { \
        int k = tid * 2 + u; \
        int gp = seg * 2048 + (CC) * 512 + k; \
        float x = pp[gp * 3 + 0], y = pp[gp * 3 + 1], z = pp[gp * 3 + 2]; \
        float hp = 0.5f * fmaf(z, z, fmaf(y, y, x * x)); \
        unsigned short xh = f2bf(x), yh = f2bf(y), zh = f2bf(z); \
        unsigned short xl = f2bf(x - bf2f(xh)), yl = f2bf(y - bf2f(yh)), zl = f2bf(z - bf2f(zh)); \
        float rr = hp; \
        unsigned short h0 = f2bf(rr); rr -= bf2f(h0); \
        unsigned short h1 = f2bf(rr); rr -= bf2f(h1); \
        unsigned short h2 = f2bf(rr); \
        UV c0, c1; \
        c0.s[0]=xh; c0.s[1]=yh; c0.s[2]=zh; c0.s[3]=xh; c0.s[4]=yh; c0.s[5]=zh; c0.s[6]=xl; c0.s[7]=yl; \
        c1.s[0]=zl; c1.s[1]=(unsigned short)(h0^0x8000); c1.s[2]=(unsigned short)(h1^0x8000); \
        c1.s[3]=(unsigned short)(h2^0x8000); c1.s[4]=0; c1.s[5]=0; c1.s[6]=0; c1.s[7]=0; \
        int t = k >> 5, pos = k & 31; \
        *(uint4*)(lb + t * 512 + pos * 8)       = c0.v; \
        *(uint4*)(lb + t * 512 + 256 + pos * 8) = c1.v; } }

#define EPILOG(MM, P) { \
    float* sc = scratch + wave * 1056; \
    _Pragma("unroll") for (int j = 0; j < 16; j++) { \
        int r0 = (j & 3) + 8 * (j >> 2) + 4 * g; sc[r0 * 33 + cc] = MM[j]; } \
    __syncthreads(); \
    const float* sr = sc + cc * 33 + g * 16; \
    float mx = -3.0e38f; \
    _Pragma("unroll") for (int k = 0; k < 16; k++) mx = fmaxf(mx, sr[k]); \
    mx = fmaxf(mx, __shfl_xor(mx, 32, 64)); \
    if (lane < 32) { \
        float d2 = 2.0f * (hq[P] - mx); \
        float d = fminf(sqrtf(fmaxf(d2, 0.0f)), TH); \
        dst[wave * 128 + (P) * 32 + lane] = d; } \
    __syncthreads(); }

__global__ __launch_bounds__(256, 3) void chamfer_kernel(
        const float* __restrict__ src, const float* __restrict__ tgt,
        float* __restrict__ d2part)
{
    const int db = blockIdx.y, dir = db >> 1, b = db & 1;
    const int rowblock = blockIdx.x >> 3, seg = blockIdx.x & 7;
    const int tid = threadIdx.x, wave = tid >> 6, lane = tid & 63;
    const int g = lane >> 5, cc = lane & 31;
    const float* qp = (dir == 0 ? src : tgt) + (size_t)b * NPTS * 3;
    const float* pp = (dir == 0 ? tgt : src) + (size_t)b * NPTS * 3;
    const unsigned short one = 0x3F80;

    // 32 KB: two 16 KB B-stage buffers; aliased as epilogue scratch after the loop
    __shared__ alignas(16) unsigned char smem[32768];
    float* scratch = (float*)smem;   // 4 waves * 32 rows * 33 floats = 16.9 KB

    // ---- A fragments + hq: registers only, each lane preps its own rows ----
    const int rt0 = rowblock * 16 + wave * 4;     // 4 row-tiles = 128 rows per wave
    bf16x8 afrag[4]; float hq[4];
#pragma unroll
    for (int i = 0; i < 4; i++) {
        int r = (rt0 + i) * 32 + cc;
        float x = qp[r * 3 + 0], y = qp[r * 3 + 1], z = qp[r * 3 + 2];
        hq[i] = 0.5f * fmaf(z, z, fmaf(y, y, x * x));
        unsigned short xh = f2bf(x), yh = f2bf(y), zh = f2bf(z);
        unsigned short xl = f2bf(x - bf2f(xh)), yl = f2bf(y - bf2f(yh)), zl = f2bf(z - bf2f(zh));
        UV f0, f1, rv;
        f0.s[0]=xh; f0.s[1]=yh; f0.s[2]=zh; f0.s[3]=xl; f0.s[4]=yl; f0.s[5]=zl; f0.s[6]=xh; f0.s[7]=yh;
        f1.s[0]=zh; f1.s[1]=one; f1.s[2]=one; f1.s[3]=one; f1.s[4]=0; f1.s[5]=0; f1.s[6]=0; f1.s[7]=0;
        rv.v = g ? f1.v : f0.v;
        afrag[i] = rv.h;
    }

    f32x16 m0 = -3.0e38f, m1 = -3.0e38f, m2 = -3.0e38f, m3 = -3.0e38f;
    const f32x16 zc = 0.0f;

    PREP_CHUNK(0, 0)
    __syncthreads();
#pragma unroll 1
    for (int c = 0; c < 4; ++c) {                 // 4 chunks x 16 col-tiles
        if (c < 3) { PREP_CHUNK(c + 1, (c + 1) & 1) }   // stage next while computing
        const unsigned short* bb = (const unsigned short*)(smem + (c & 1) * 16384);
        // software-pipelined pt loop: prefetch q for pt+1 before folding pt,
        // so the ~120-cyc ds_read latency is covered by the ~256-cyc fold chain
        bf16x8 q0 = *(const bf16x8*)(bb + lane * 8);
        bf16x8 q1 = *(const bf16x8*)(bb + 512 + lane * 8);
#pragma unroll 1
        for (int pt = 0; pt < 8; ++pt) {          // 2 col-tiles per iter
            const int np = (pt + 1) & 7;          // wrap: one redundant re-read per chunk
            bf16x8 r0 = *(const bf16x8*)(bb + np * 1024 + lane * 8);
            bf16x8 r1 = *(const bf16x8*)(bb + np * 1024 + 512 + lane * 8);
            FOLD2(m0, afrag[0])
            FOLD2(m1, afrag[1])
            FOLD2(m2, afrag[2])
            FOLD2(m3, afrag[3])
            q0 = r0; q1 = r1;
        }
        __syncthreads();
    }

    float* dst = d2part + (((size_t)(db * 32 + rowblock)) * 8 + seg) * 512;
    EPILOG(m0, 0)
    EPILOG(m1, 1)
    EPILOG(m2, 2)
    EPILOG(m3, 3)
}

__global__ __launch_bounds__(256) void merge_kernel(const float* __restrict__ d2part,
                                                    float* __restrict__ out) {
    const int b = blockIdx.y;                     // batch
    const int slice = blockIdx.x;                 // 16 slices of 1024 rows
    const int tid = threadIdx.x;
    float s = 0.0f;
#pragma unroll
    for (int pass = 0; pass < 2; pass++) {        // dir 0 and dir 1
        const float* base = d2part + (size_t)(pass * 2 + b) * 32 * 8 * 512;
#pragma unroll
        for (int i = 0; i < 4; i++) {
            int r = slice * 1024 + i * 256 + tid;
            const float* p = base + (size_t)(r >> 9) * 4096 + (r & 511);
            float m = p[0];
#pragma unroll
            for (int sgi = 1; sgi < 8; sgi++) m = fminf(m, p[sgi * 512]);
            s += m;
        }
    }
#pragma unroll
    for (int off = 32; off > 0; off >>= 1) s += __shfl_down(s, off, 64);
    __shared__ float w[4];
    if ((tid & 63) == 0) w[tid >> 6] = s;
    __syncthreads();
    if (tid == 0) {
        float t = (w[0] + w[1]) + (w[2] + w[3]);
        atomicAdd(&out[b], t * (1.0f / (2.0f * NPTS)));  // (mean_fwd + mean_bwd) / 2
    }
}

extern "C" void kernel_launch(void* const* d_in, const int* in_sizes, int n_in,
                              void* d_out, int out_size, void* d_ws, size_t ws_size,
                              hipStream_t stream) {
    const float* src = (const float*)d_in[0];
    const float* tgt = (const float*)d_in[1];
    float* out = (float*)d_out;
    float* d2part = (float*)d_ws;                 // 2 MB, write-once (no init needed)

    hipMemsetAsync(out, 0, 2 * sizeof(float), stream);   // async: graph-capturable
    chamfer_kernel<<<dim3(256, 4), 256, 0, stream>>>(src, tgt, d2part);
    merge_kernel<<<dim3(16, 2), 256, 0, stream>>>(d2part, out);
}